// Round 4
// baseline (88.159 us; speedup 1.0000x reference)
//
#include <hip/hip_runtime.h>
#include <stdint.h>

#define NTIPS 128
#define NSITES 1024
#define BS 32
#define STEPS 127          // ntips-1 postorder merge steps
#define NNODES 255         // 2*ntips-1 state slots
#define SB 64              // sites per block (one wave, one site per lane)

// Pack one-hot int32 L[tip][5][site] -> 5-bit mask byte packed[tip][site].
// Block 0 also zeroes the 32 output accumulators (graph-capture-safe, runs
// before fitch_kernel in stream order every launch).
__global__ __launch_bounds__(256) void pack_leaves(const int* __restrict__ L,
                                                   uint8_t* __restrict__ packed,
                                                   int* __restrict__ out) {
    int i = blockIdx.x * 256 + threadIdx.x;       // 0 .. 128*1024-1
    if (blockIdx.x == 0 && threadIdx.x < BS) out[threadIdx.x] = 0;
    int tip = i >> 10, site = i & 1023;
    const int* b = L + tip * 5 * NSITES + site;
    int m = b[0] | (b[NSITES] << 1) | (b[2 * NSITES] << 2) |
            (b[3 * NSITES] << 3) | (b[4 * NSITES] << 4);
    packed[i] = (uint8_t)m;
}

__global__ __launch_bounds__(64) void fitch_kernel(const int* __restrict__ L,
                                                   const int* __restrict__ site_counts,
                                                   const int* __restrict__ pairs,
                                                   const uint8_t* __restrict__ packed,
                                                   int use_packed,
                                                   int* __restrict__ out) {
    // Unified per-site state column: rows 0..127 leaves, 128..254 internal.
    // Each lane only ever READS column `tid`; staging writes cross columns.
    __shared__ uint8_t state[NNODES][SB];     // ~16 KiB

    const int tid      = threadIdx.x;
    const int batch    = blockIdx.x >> 4;       // 32 batches
    const int siteBase = (blockIdx.x & 15) * SB;
    const int site     = siteBase + tid;

    if (use_packed) {
        // 8 KB slice of packed masks -> LDS, dword-wide (32 dwords/lane).
        #pragma unroll 8
        for (int k = 0; k < 32; ++k) {
            int i = (k << 6) + tid;             // 0..2047 dwords
            int t = i >> 4, j = i & 15;         // tip, dword-in-64B-row
            uint32_t d = *(const uint32_t*)(packed + (t << 10) + siteBase + (j << 2));
            ((uint32_t*)state)[i] = d;          // state rows are 64B -> direct map
        }
    } else {
        // Fallback: build masks straight from one-hot L (coalesced dword loads).
        const int* Lp = L + site;
        #pragma unroll 8
        for (int t = 0; t < NTIPS; ++t) {
            const int* b = Lp + t * 5 * NSITES;
            int m = b[0] | (b[NSITES] << 1) | (b[2 * NSITES] << 2) |
                    (b[3 * NSITES] << 3) | (b[4 * NSITES] << 4);
            state[t][tid] = (uint8_t)m;
        }
    }
    __syncthreads();

    // 127 Fitch merges, branchless. Child addresses depend only on scalar
    // pair data (s_load, blockIdx-uniform) -> ds_reads prefetch ahead under
    // unrolling. The loop-carried value forwards via cndmask (c == lastP);
    // the stale LDS read in that case is discarded, so no RAW stall.
    const int* pb = pairs + batch * 3;
    int lastP = -1;
    int lastV = 0;
    int score = 0;
    #pragma unroll 8
    for (int s = 0; s < STEPS; ++s) {
        const int c0 = pb[s * (BS * 3)];
        const int c1 = pb[s * (BS * 3) + 1];
        const int p  = pb[s * (BS * 3) + 2];
        int r0 = (int)state[c0][tid];
        int r1 = (int)state[c1][tid];
        int m0 = (c0 == lastP) ? lastV : r0;
        int m1 = (c1 == lastP) ? lastV : r1;
        int inter = m0 & m1;
        int nxt   = inter ? inter : (m0 | m1);
        score    += (inter == 0);
        state[p][tid] = (uint8_t)nxt;
        lastP = p;
        lastV = nxt;
    }

    // Weighted per-site score -> per-batch sum. int32-exact (max < 2^24).
    int val = score * site_counts[site];
    #pragma unroll
    for (int off = 32; off; off >>= 1) val += __shfl_down(val, off);
    if (tid == 0) atomicAdd(&out[batch], val);
}

extern "C" void kernel_launch(void* const* d_in, const int* in_sizes, int n_in,
                              void* d_out, int out_size, void* d_ws, size_t ws_size,
                              hipStream_t stream) {
    const int* L           = (const int*)d_in[0];
    const int* site_counts = (const int*)d_in[1];
    const int* pairs       = (const int*)d_in[2];
    int* out               = (int*)d_out;

    const size_t packed_bytes = (size_t)NTIPS * NSITES;  // 128 KiB
    int use_packed = (ws_size >= packed_bytes) ? 1 : 0;
    uint8_t* packed = (uint8_t*)d_ws;

    if (use_packed) {
        // pack_leaves also zeroes out[] (block 0), saving a fill dispatch.
        pack_leaves<<<dim3((NTIPS * NSITES) / 256), dim3(256), 0, stream>>>(L, packed, out);
    } else {
        hipMemsetAsync(out, 0, BS * sizeof(int), stream);
    }
    fitch_kernel<<<dim3(BS * (NSITES / SB)), dim3(64), 0, stream>>>(
        L, site_counts, pairs, packed, use_packed, out);
}

// Round 5
// 82.382 us; speedup vs baseline: 1.0701x; 1.0701x over previous
//
#include <hip/hip_runtime.h>
#include <stdint.h>

#define NTIPS 128
#define NSITES 1024
#define BS 32
#define STEPS 127          // ntips-1 postorder merge steps
#define NINTERNAL 127      // internal-node state slots (general path only)

// One block per batch (1024 threads = one site per lane, 16 waves).
// Caterpillar fast path: zero stores in the 127-step serial loop -> the
// loop-carried dep is a ~3-VALU register chain; leaf masks are built from
// one-hot L with prefetchable, coalesced dword loads (L2-resident, 2.6 MB).
// Block-level reduce writes out[b] with a plain store: no atomics, no
// out-zero memset, no pack kernel, no LDS state. Single dispatch.
__global__ __launch_bounds__(1024) void fitch_kernel(
    const int* __restrict__ L,
    const int* __restrict__ site_counts,
    const int* __restrict__ pairs,
    uint8_t* __restrict__ ws,      // scratch for general-topology fallback only
    int* __restrict__ out)
{
    __shared__ int spairs[STEPS * 3];
    __shared__ int wsum[16];
    __shared__ int allvalid;

    const int tid  = threadIdx.x;
    const int b    = blockIdx.x;       // batch
    const int site = tid;              // one site per lane

    if (tid == 0) allvalid = 1;
    // Stage this batch's pairs: pairs[s][b][j], flat = s*96 + b*3 + j.
    if (tid < STEPS * 3) {
        int s = tid / 3, j = tid - s * 3;
        spairs[tid] = pairs[s * (BS * 3) + b * 3 + j];
    }
    __syncthreads();

    // Validate caterpillar structure (sufficient for fast-path equivalence):
    //   every c1 is a leaf; c0(0) is a leaf; c0(s)=p(s-1); every p >= NTIPS
    // Under these, the scan is exactly cur = merge(cur, leaf(c1(s))) and no
    // state slot that is ever read gets clobbered.
    if (tid < STEPS) {
        int c0 = spairs[3 * tid], c1 = spairs[3 * tid + 1], p = spairs[3 * tid + 2];
        bool v = (c1 >= 0) && (c1 < NTIPS) && (p >= NTIPS) &&
                 (tid == 0 ? (c0 >= 0 && c0 < NTIPS)
                           : (c0 == spairs[3 * (tid - 1) + 2]));
        if (!v) allvalid = 0;          // benign race: all writers store 0
    }
    __syncthreads();

    const int* Lp = L + site;
    int score = 0;

    #define LEAFMASK(q) ((q)[0] | ((q)[NSITES] << 1) | ((q)[2 * NSITES] << 2) | \
                         ((q)[3 * NSITES] << 3) | ((q)[4 * NSITES] << 4))

    if (allvalid) {
        // ---- fast path: store-free serial chain ----
        int c00 = __builtin_amdgcn_readfirstlane(spairs[0]);
        const int* q0 = Lp + c00 * 5 * NSITES;
        int cur = LEAFMASK(q0);
        #pragma unroll 8
        for (int s = 0; s < STEPS; ++s) {
            int c1 = __builtin_amdgcn_readfirstlane(spairs[3 * s + 1]);
            const int* q = Lp + c1 * 5 * NSITES;
            int m1 = LEAFMASK(q);
            int inter = cur & m1;
            score += (inter == 0);
            cur = inter ? inter : (cur | m1);
        }
    } else {
        // ---- general postorder fallback (not taken for caterpillar input) ----
        // Per-batch internal-node state in global scratch; postorder guarantees
        // write-before-read, so the 0xAA poison is never observed.
        uint8_t* st = ws + (size_t)b * NINTERNAL * NSITES;
        int lastP = -1, lastV = 0;
        for (int s = 0; s < STEPS; ++s) {
            int c0 = __builtin_amdgcn_readfirstlane(spairs[3 * s]);
            int c1 = __builtin_amdgcn_readfirstlane(spairs[3 * s + 1]);
            int p  = __builtin_amdgcn_readfirstlane(spairs[3 * s + 2]);
            int m0, m1;
            if (c0 == lastP)        m0 = lastV;
            else if (c0 < NTIPS)  { const int* q = Lp + c0 * 5 * NSITES; m0 = LEAFMASK(q); }
            else                    m0 = st[(c0 - NTIPS) * NSITES + site];
            if (c1 == lastP)        m1 = lastV;
            else if (c1 < NTIPS)  { const int* q = Lp + c1 * 5 * NSITES; m1 = LEAFMASK(q); }
            else                    m1 = st[(c1 - NTIPS) * NSITES + site];
            int inter = m0 & m1;
            int nxt   = inter ? inter : (m0 | m1);
            score    += (inter == 0);
            st[(p - NTIPS) * NSITES + site] = (uint8_t)nxt;
            lastP = p; lastV = nxt;
        }
    }

    // Weighted per-site score -> per-batch sum, block reduce, plain store.
    int val = score * site_counts[site];
    #pragma unroll
    for (int off = 32; off; off >>= 1) val += __shfl_down(val, off);
    if ((tid & 63) == 0) wsum[tid >> 6] = val;
    __syncthreads();
    if (tid == 0) {
        int t = 0;
        #pragma unroll
        for (int i = 0; i < 16; ++i) t += wsum[i];
        out[b] = t;                     // full overwrite; no zeroing needed
    }
}

extern "C" void kernel_launch(void* const* d_in, const int* in_sizes, int n_in,
                              void* d_out, int out_size, void* d_ws, size_t ws_size,
                              hipStream_t stream) {
    const int* L           = (const int*)d_in[0];
    const int* site_counts = (const int*)d_in[1];
    const int* pairs       = (const int*)d_in[2];
    fitch_kernel<<<dim3(BS), dim3(1024), 0, stream>>>(
        L, site_counts, pairs, (uint8_t*)d_ws, (int*)d_out);
}

// Round 8
// 70.703 us; speedup vs baseline: 1.2469x; 1.1652x over previous
//
#include <hip/hip_runtime.h>
#include <stdint.h>

#define NTIPS 128
#define NSITES 1024
#define BS 32
#define STEPS 127          // ntips-1 postorder merge steps
#define NNODES 255         // 2*ntips-1 state slots
#define SB 64              // sites per block (one wave)
#define GPB 16             // site-group blocks per batch (1024/64)

// 512 blocks x 64 threads: one wave per block, one (batch, 64-site group)
// each. Caterpillar fast path: zero stores in the 127-step serial loop; the
// loop-carried dep is ~3 VALU ops/step, leaf masks built from one-hot L with
// coalesced, unroll-prefetched dword loads (L2-resident). 2 blocks/CU ->
// per-SIMD VALU issue is 4x lower than the one-block-per-batch layout.
__global__ __launch_bounds__(64) void fitch_kernel(
    const int* __restrict__ L,
    const int* __restrict__ site_counts,
    const int* __restrict__ pairs,
    uint8_t* __restrict__ ws,      // scratch for general-topology fallback only
    int* __restrict__ out)
{
    __shared__ int sc0[STEPS];
    __shared__ int sc1[STEPS];
    __shared__ int sp[STEPS];
    __shared__ int sinvalid;

    const int tid  = threadIdx.x;
    const int b    = blockIdx.x >> 4;   // batch
    const int g    = blockIdx.x & (GPB - 1);
    const int site = (g << 6) + tid;

    if (tid == 0) sinvalid = 0;

    // Stage this batch's triples (pairs[s][b][j], flat s*96 + b*3 + j) and
    // validate the caterpillar property:
    //   c1 always a leaf, c0(0) a leaf, c0(s)=p(s-1), p always internal.
    // Under these the scan is exactly cur = merge(cur, leaf(c1(s))): c0 reads
    // are register-forwarded and no slot that is ever read gets clobbered.
    int c0a[2];
    bool bad = false;
    #pragma unroll
    for (int k = 0; k < 2; ++k) {
        int i = tid + (k << 6);
        if (i < STEPS) {
            const int* pp = pairs + i * (BS * 3) + b * 3;
            int c0 = pp[0], c1 = pp[1], p = pp[2];
            sc0[i] = c0; sc1[i] = c1; sp[i] = p;
            c0a[k] = c0;
            bad |= ((unsigned)c1 >= NTIPS) || (p < NTIPS) || (p >= NNODES);
        }
    }
    __syncthreads();
    #pragma unroll
    for (int k = 0; k < 2; ++k) {
        int i = tid + (k << 6);
        if (i < STEPS)
            bad |= (i == 0) ? ((unsigned)c0a[k] >= NTIPS) : (c0a[k] != sp[i - 1]);
    }
    if (bad) sinvalid = 1;
    __syncthreads();

    const int* Lp = L + site;
    int score = 0;

    #define LEAFMASK(q) ((q)[0] | ((q)[NSITES] << 1) | ((q)[2 * NSITES] << 2) | \
                         ((q)[3 * NSITES] << 3) | ((q)[4 * NSITES] << 4))

    if (!sinvalid) {
        // ---- fast path: store-free serial chain ----
        int c00 = __builtin_amdgcn_readfirstlane(sc0[0]);
        const int* q0 = Lp + c00 * 5 * NSITES;
        int cur = LEAFMASK(q0);
        #pragma unroll 8
        for (int s = 0; s < STEPS; ++s) {
            int c1 = __builtin_amdgcn_readfirstlane(sc1[s]);
            const int* q = Lp + c1 * 5 * NSITES;
            int m1 = LEAFMASK(q);
            int inter = cur & m1;
            score += (inter == 0);
            cur = inter ? inter : (cur | m1);
        }
    } else {
        // ---- general postorder fallback (never taken for caterpillar input) ----
        // Per-block internal-state columns in global scratch; postorder
        // guarantees write-before-read; single wave -> in-order.
        uint8_t* st = ws + (size_t)blockIdx.x * STEPS * SB;
        int lastP = -1, lastV = 0;
        for (int s = 0; s < STEPS; ++s) {
            int c0 = __builtin_amdgcn_readfirstlane(sc0[s]);
            int c1 = __builtin_amdgcn_readfirstlane(sc1[s]);
            int p  = __builtin_amdgcn_readfirstlane(sp[s]);
            int m0, m1;
            if (c0 == lastP)       m0 = lastV;
            else if (c0 < NTIPS) { const int* q = Lp + c0 * 5 * NSITES; m0 = LEAFMASK(q); }
            else                   m0 = st[(c0 - NTIPS) * SB + tid];
            if (c1 == lastP)       m1 = lastV;
            else if (c1 < NTIPS) { const int* q = Lp + c1 * 5 * NSITES; m1 = LEAFMASK(q); }
            else                   m1 = st[(c1 - NTIPS) * SB + tid];
            int inter = m0 & m1;
            int nxt   = inter ? inter : (m0 | m1);
            score    += (inter == 0);
            st[(p - NTIPS) * SB + tid] = (uint8_t)nxt;
            lastP = p; lastV = nxt;
        }
    }

    // Weighted per-site score -> wave reduce -> one atomic per block.
    int val = score * site_counts[site];
    #pragma unroll
    for (int off = 32; off; off >>= 1) val += __shfl_down(val, off);
    if (tid == 0) atomicAdd(&out[b], val);
}

extern "C" void kernel_launch(void* const* d_in, const int* in_sizes, int n_in,
                              void* d_out, int out_size, void* d_ws, size_t ws_size,
                              hipStream_t stream) {
    const int* L           = (const int*)d_in[0];
    const int* site_counts = (const int*)d_in[1];
    const int* pairs       = (const int*)d_in[2];
    int* out               = (int*)d_out;

    // d_out is poisoned 0xAA before every launch -> zero it (capture-safe).
    hipMemsetAsync(out, 0, BS * sizeof(int), stream);
    fitch_kernel<<<dim3(BS * GPB), dim3(SB), 0, stream>>>(
        L, site_counts, pairs, (uint8_t*)d_ws, out);
}